// Round 1
// baseline (302.915 us; speedup 1.0000x reference)
//
#include <hip/hip_runtime.h>

typedef float  f32x4 __attribute__((ext_vector_type(4)));
typedef short  s16x8 __attribute__((ext_vector_type(8)));
typedef unsigned short u16;

// ---- workspace layout (bytes) ----
#define OFF_E     0ULL            // e  bf16 LDS-image tiles [512][32KiB]   16 MiB
#define OFF_ET    16777216ULL     // eT bf16 LDS-image tiles [512][32KiB]   16 MiB
#define OFF_EPART 33554432ULL     // Epart f32 [16][8][512][128]            32 MiB
#define OFF_GT    67108864ULL     // Gt bf16 LDS-image tiles [32][32KiB]     1 MiB
#define OFF_WT    68157440ULL     // Wt bf16 LDS-image tiles [8][16KiB]    128 KiB
#define OFF_ZP    68288512ULL     // zpart f32 [512][128]                  256 KiB
#define OFF_RZ2   68550656ULL     // rz2 f32 [1024]                          4 KiB
#define WS_NEED   68554752ULL

// async global->LDS, 16B per lane, wave-uniform LDS base + lane*16
#define GLL16(g, l)                                                          \
  __builtin_amdgcn_global_load_lds(                                          \
      (const __attribute__((address_space(1))) void*)(g),                    \
      (__attribute__((address_space(3))) void*)(l), 16, 0, 0)

__device__ __forceinline__ u16 f2bf(float f) {
  unsigned u = __float_as_uint(f);
  return (u16)((u + 0x8000u) >> 16);          // round-half-up to bf16
}
__device__ __forceinline__ unsigned pack2(float a, float b) {
  unsigned ua = __float_as_uint(a), ub = __float_as_uint(b);
  return ((ua + 0x8000u) >> 16) | ((ub + 0x8000u) & 0xffff0000u);
}

// ------------------------------------------------------------------
// k_wt: Wt stored as k_logits_e's lB LDS image:
//   img[kt][h*64 + ((oct ^ (h&7))*8) + t] = W[kt*64 + oct*8 + t][h]
__global__ __launch_bounds__(256) void k_wt(const float* __restrict__ W,
                                            u16* __restrict__ WtImg) {
  int idx = blockIdx.x * 256 + threadIdx.x;    // 65536 total
  int h = idx & 127, c = idx >> 7;
  int kt = c >> 6, oct = (c >> 3) & 7, t = c & 7;
  WtImg[kt * 8192 + h * 64 + ((oct ^ (h & 7)) * 8) + t] = f2bf(W[c * 128 + h]);
}

// ------------------------------------------------------------------
// k_logits_e: per 128-row tile: logits = x@Wt (bf16 MFMA), then
// e = exp(logits) -> writes e-image (raw sm dump) + eT-image, and
// per-column partial sums of e (zpart).
__global__ __launch_bounds__(256) void k_logits_e(
    const float* __restrict__ x, const u16* __restrict__ WtImg,
    u16* __restrict__ eImg, u16* __restrict__ eTImg, float* __restrict__ zpart) {
  __shared__ __align__(16) u16 sm[128 * 128];
  __shared__ float zs[512];
  u16* lA = sm;
  u16* lB = sm + 8192;
  const int tid = threadIdx.x;
  const int lane = tid & 63, wave = tid >> 6;
  const int l15 = lane & 15, quad = lane >> 4;
  const int mt = blockIdx.x;                   // 0..511  (== b*64 + sc)
  const int rowBase = mt << 7;

  f32x4 acc[2][8];
#pragma unroll
  for (int i = 0; i < 2; ++i)
#pragma unroll
    for (int j = 0; j < 8; ++j) acc[i][j] = (f32x4){0.f, 0.f, 0.f, 0.f};

  for (int kt = 0; kt < 8; ++kt) {
    const int k0 = kt << 6;
    if (kt) __syncthreads();
    // ---- stage B: Wt image via global_load_lds (issue first, async)
    {
      const char* src = (const char*)WtImg + (size_t)kt * 16384 + wave * 4096 + lane * 16;
      char* dst = (char*)lB + wave * 4096;
#pragma unroll
      for (int i = 0; i < 4; ++i) GLL16(src + i * 1024, dst + i * 1024);
    }
    // ---- stage A: x fp32 -> bf16 pack (unchanged)
    {
      const int q = tid & 3, rb = tid >> 2;
#pragma unroll
      for (int rep = 0; rep < 2; ++rep) {
        const int r = rb + rep * 64;
        const float* src = x + (size_t)(rowBase + r) * 512 + k0 + q * 4;
#pragma unroll
        for (int j = 0; j < 4; ++j) {
          f32x4 v = *(const f32x4*)(src + j * 16);
          const int chunk = (2 * j + (q >> 1)) ^ (r & 7);
          unsigned* dst = (unsigned*)&lA[r * 64 + chunk * 8 + (q & 1) * 4];
          dst[0] = pack2(v[0], v[1]);
          dst[1] = pack2(v[2], v[3]);
        }
      }
    }
    __syncthreads();
#pragma unroll
    for (int kk = 0; kk < 2; ++kk) {
      s16x8 af[2], bf[8];
#pragma unroll
      for (int i = 0; i < 2; ++i) {
        const int r = wave * 32 + i * 16 + l15;
        af[i] = *(const s16x8*)&lA[r * 64 + (((kk * 4 + quad) ^ (r & 7)) * 8)];
      }
#pragma unroll
      for (int j = 0; j < 8; ++j) {
        const int r = j * 16 + l15;
        bf[j] = *(const s16x8*)&lB[r * 64 + (((kk * 4 + quad) ^ (r & 7)) * 8)];
      }
#pragma unroll
      for (int i = 0; i < 2; ++i)
#pragma unroll
        for (int j = 0; j < 8; ++j)
          acc[i][j] = __builtin_amdgcn_mfma_f32_16x16x32_bf16(af[i], bf[j], acc[i][j], 0, 0, 0);
    }
  }

  float ex[2][8][4];
  float cs[8];
#pragma unroll
  for (int j = 0; j < 8; ++j) cs[j] = 0.f;
#pragma unroll
  for (int i = 0; i < 2; ++i)
#pragma unroll
    for (int j = 0; j < 8; ++j)
#pragma unroll
      for (int rr = 0; rr < 4; ++rr) {
        float l = acc[i][j][rr];
        l = fminf(fmaxf(l, -30.f), 30.f);
        float t = __expf(l);
        ex[i][j][rr] = t;
        cs[j] += t;
      }
#pragma unroll
  for (int j = 0; j < 8; ++j) {
    cs[j] += __shfl_xor(cs[j], 16);
    cs[j] += __shfl_xor(cs[j], 32);
  }
  if (quad == 0) {
#pragma unroll
    for (int j = 0; j < 8; ++j) zs[wave * 128 + j * 16 + l15] = cs[j];
  }
  __syncthreads();

#pragma unroll
  for (int i = 0; i < 2; ++i)
#pragma unroll
    for (int j = 0; j < 8; ++j)
#pragma unroll
      for (int rr = 0; rr < 4; ++rr) {
        int s = wave * 32 + i * 16 + quad * 4 + rr;
        int h = j * 16 + l15;
        sm[s * 128 + (((h >> 3) ^ (s & 15)) * 8) + (h & 7)] = f2bf(ex[i][j][rr]);
      }
  if (tid < 128)
    zpart[mt * 128 + tid] = zs[tid] + zs[128 + tid] + zs[256 + tid] + zs[384 + tid];
  __syncthreads();

  // ---- e image: raw linear dump of sm (sm layout == k_out lA image)
  {
    char* dstT = (char*)eImg + (size_t)mt * 32768;
    const char* smB = (const char*)sm;
#pragma unroll
    for (int pass = 0; pass < 8; ++pass) {
      s16x8 v = *(const s16x8*)(smB + pass * 4096 + tid * 16);
      *(s16x8*)(dstT + pass * 4096 + tid * 16) = v;
    }
  }
  // ---- eT image: gather transpose, store in k_E's lB image order
  {
    int ck = tid & 15, hb = tid >> 4;
    u16* dstT = eTImg + (size_t)mt * 16384;
#pragma unroll
    for (int pass = 0; pass < 8; ++pass) {
      int h = hb + pass * 16;
      int key = ((h >> 3) ^ (h << 1)) & 15;
      s16x8 v;
#pragma unroll
      for (int j = 0; j < 8; ++j) {
        int s = ck * 8 + j;
        v[j] = (short)sm[s * 128 + (((h >> 3) ^ (s & 15)) * 8) + (h & 7)];
      }
      *(s16x8*)(dstT + h * 128 + ((ck ^ key) * 8)) = v;
    }
  }
}

// ------------------------------------------------------------------
// k_zmerge: Z per (b,h), store 1/Z^2
__global__ __launch_bounds__(256) void k_zmerge(const float* __restrict__ zpart,
                                                float* __restrict__ rz2) {
  int gid = blockIdx.x * 256 + threadIdx.x;  // 0..1023
  int b = gid >> 7, h = gid & 127;
  float z = 0.f;
  for (int i = 0; i < 64; ++i) z += zpart[(b * 64 + i) * 128 + h];
  rz2[gid] = 1.0f / (z * z);
}

// ------------------------------------------------------------------
// k_E: E^T[c][h] = sum_s x[s][c]*eT[h][s].  x read fp32 DIRECTLY and
// transposed into LDS during staging.  eT staged via global_load_lds from
// its pre-swizzled image (content bit-identical to old reg-staged path).
__global__ __launch_bounds__(256) void k_E(const float* __restrict__ x,
                                           const u16* __restrict__ eTImg,
                                           float* __restrict__ Epart) {
  __shared__ __align__(16) u16 lA[128 * 128];   // [c][s]  32 KiB
  __shared__ __align__(16) u16 lB[128 * 128];   // [h][s]  32 KiB
  const int tid = threadIdx.x;
  const int lane = tid & 63, wave = tid >> 6;
  const int l15 = lane & 15, quad = lane >> 4;
  const int nt = blockIdx.x;   // c band 0..3 (128 wide)
  const int b = blockIdx.y;
  const int kc = blockIdx.z;   // 0..15: 512-s chunk

  f32x4 acc[2][8];
#pragma unroll
  for (int i = 0; i < 2; ++i)
#pragma unroll
    for (int j = 0; j < 8; ++j) acc[i][j] = (f32x4){0.f, 0.f, 0.f, 0.f};

  const int cw = tid & 15, rg = tid >> 4;

  for (int kt = 0; kt < 4; ++kt) {
    if (kt) __syncthreads();
    // ---- stage B: eT image via global_load_lds (issue first, async)
    {
      const char* src = (const char*)eTImg + ((size_t)(b * 64 + kc * 4 + kt) * 32768) +
                        wave * 8192 + lane * 16;
      char* dst = (char*)lB + wave * 8192;
#pragma unroll
      for (int i = 0; i < 8; ++i) GLL16(src + i * 1024, dst + i * 1024);
    }
    // ---- stage A: x[sb+rg*8+j][nt*128+cw*8+i] -> lA[c][s], transpose in reg
    {
      const int sb = kc * 512 + kt * 128;
      const float* src = x + ((size_t)(b * 8192 + sb + rg * 8) * 512 + nt * 128 + cw * 8);
      f32x4 v0[8], v1[8];
#pragma unroll
      for (int j = 0; j < 8; ++j) {
        v0[j] = *(const f32x4*)(src + (size_t)j * 512);
        v1[j] = *(const f32x4*)(src + (size_t)j * 512 + 4);
      }
#pragma unroll
      for (int i = 0; i < 8; ++i) {
        const int cl = cw * 8 + i;
        const int key = ((cl >> 3) ^ (cl << 1)) & 15;
        unsigned wv[4];
        if (i < 4) {
          wv[0] = pack2(v0[0][i & 3], v0[1][i & 3]);
          wv[1] = pack2(v0[2][i & 3], v0[3][i & 3]);
          wv[2] = pack2(v0[4][i & 3], v0[5][i & 3]);
          wv[3] = pack2(v0[6][i & 3], v0[7][i & 3]);
        } else {
          wv[0] = pack2(v1[0][i & 3], v1[1][i & 3]);
          wv[1] = pack2(v1[2][i & 3], v1[3][i & 3]);
          wv[2] = pack2(v1[4][i & 3], v1[5][i & 3]);
          wv[3] = pack2(v1[6][i & 3], v1[7][i & 3]);
        }
        *(s16x8*)&lA[cl * 128 + ((rg ^ key) * 8)] = *(const s16x8*)wv;
      }
    }
    __syncthreads();
#pragma unroll
    for (int kk = 0; kk < 4; ++kk) {
      s16x8 af[2], bf[8];
#pragma unroll
      for (int i = 0; i < 2; ++i) {
        const int r = wave * 32 + i * 16 + l15;
        const int key = ((r >> 3) ^ (r << 1)) & 15;
        af[i] = *(const s16x8*)&lA[r * 128 + (((kk * 4 + quad) ^ key) * 8)];
      }
#pragma unroll
      for (int j = 0; j < 8; ++j) {
        const int n = j * 16 + l15;
        const int key = ((n >> 3) ^ (n << 1)) & 15;
        bf[j] = *(const s16x8*)&lB[n * 128 + (((kk * 4 + quad) ^ key) * 8)];
      }
#pragma unroll
      for (int i = 0; i < 2; ++i)
#pragma unroll
        for (int j = 0; j < 8; ++j)
          acc[i][j] = __builtin_amdgcn_mfma_f32_16x16x32_bf16(af[i], bf[j], acc[i][j], 0, 0, 0);
    }
  }
  float* dst = Epart + ((size_t)(kc * 8 + b) * 512 + nt * 128) * 128;
#pragma unroll
  for (int i = 0; i < 2; ++i)
#pragma unroll
    for (int j = 0; j < 8; ++j)
#pragma unroll
      for (int rr = 0; rr < 4; ++rr) {
        int c = wave * 32 + i * 16 + quad * 4 + rr;
        int h = j * 16 + l15;
        dst[(size_t)c * 128 + h] = acc[i][j][rr];
      }
}

// ------------------------------------------------------------------
// k_G: Gt image[b][ct][r*128 + ((h8 ^ (r&15))*8)+t] = bf16(E * rz2)
__global__ __launch_bounds__(256) void k_G(const float* __restrict__ Epart,
                                           const float* __restrict__ rz2,
                                           u16* __restrict__ GtImg) {
  int idx = blockIdx.x * 256 + threadIdx.x;  // 65536 threads, 8 h each
  int h8 = idx & 15, c = (idx >> 4) & 511, b = idx >> 13;
  f32x4 s0 = {0.f, 0.f, 0.f, 0.f}, s1 = {0.f, 0.f, 0.f, 0.f};
#pragma unroll
  for (int p = 0; p < 16; ++p) {
    const float* src = Epart + (((size_t)(p * 8 + b) * 512 + c) * 128 + h8 * 8);
    s0 += *(const f32x4*)src;
    s1 += *(const f32x4*)(src + 4);
  }
  const float* rz = rz2 + b * 128 + h8 * 8;
  f32x4 z0 = *(const f32x4*)rz;
  f32x4 z1 = *(const f32x4*)(rz + 4);
  unsigned ov[4];
  ov[0] = pack2(s0[0] * z0[0], s0[1] * z0[1]);
  ov[1] = pack2(s0[2] * z0[2], s0[3] * z0[3]);
  ov[2] = pack2(s1[0] * z1[0], s1[1] * z1[1]);
  ov[3] = pack2(s1[2] * z1[2], s1[3] * z1[3]);
  int r = c & 127, ct = c >> 7;
  *(s16x8*)(GtImg + ((size_t)(b * 4 + ct) * 16384) + r * 128 + ((h8 ^ (r & 15)) * 8)) =
      *(s16x8*)ov;
}

// ------------------------------------------------------------------
// k_out: out[s][c] = e[s][:] @ G[:, c].  Both operands staged purely via
// global_load_lds from pre-swizzled images; fragment reads unchanged.
__global__ __launch_bounds__(256) void k_out(const u16* __restrict__ eImg,
                                             const u16* __restrict__ GtImg,
                                             float* __restrict__ out) {
  __shared__ __align__(16) u16 lA[128 * 128];
  __shared__ __align__(16) u16 lB[128 * 128];
  const int tid = threadIdx.x;
  const int lane = tid & 63, wave = tid >> 6;
  const int l15 = lane & 15, quad = lane >> 4;
  const int st = blockIdx.x;
  const int b = blockIdx.y;

  // ---- stage A: e image (once)
  {
    const char* src = (const char*)eImg + ((size_t)(b * 64 + st) * 32768) +
                      wave * 8192 + lane * 16;
    char* dst = (char*)lA + wave * 8192;
#pragma unroll
    for (int i = 0; i < 8; ++i) GLL16(src + i * 1024, dst + i * 1024);
  }
  for (int ct = 0; ct < 4; ++ct) {
    if (ct) __syncthreads();
    // ---- stage B: Gt image
    {
      const char* src = (const char*)GtImg + ((size_t)(b * 4 + ct) * 32768) +
                        wave * 8192 + lane * 16;
      char* dst = (char*)lB + wave * 8192;
#pragma unroll
      for (int i = 0; i < 8; ++i) GLL16(src + i * 1024, dst + i * 1024);
    }
    __syncthreads();
    f32x4 acc[2][8];
#pragma unroll
    for (int i = 0; i < 2; ++i)
#pragma unroll
      for (int j = 0; j < 8; ++j) acc[i][j] = (f32x4){0.f, 0.f, 0.f, 0.f};
#pragma unroll
    for (int kk = 0; kk < 4; ++kk) {
      s16x8 af[2], bf[8];
#pragma unroll
      for (int i = 0; i < 2; ++i) {
        const int r = wave * 32 + i * 16 + l15;
        af[i] = *(const s16x8*)&lA[r * 128 + (((kk * 4 + quad) ^ (r & 15)) * 8)];
      }
#pragma unroll
      for (int j = 0; j < 8; ++j) {
        const int n = j * 16 + l15;
        bf[j] = *(const s16x8*)&lB[n * 128 + (((kk * 4 + quad) ^ (n & 15)) * 8)];
      }
#pragma unroll
      for (int i = 0; i < 2; ++i)
#pragma unroll
        for (int j = 0; j < 8; ++j)
          acc[i][j] = __builtin_amdgcn_mfma_f32_16x16x32_bf16(af[i], bf[j], acc[i][j], 0, 0, 0);
    }
#pragma unroll
    for (int i = 0; i < 2; ++i)
#pragma unroll
      for (int j = 0; j < 8; ++j)
#pragma unroll
        for (int rr = 0; rr < 4; ++rr) {
          int s = wave * 32 + i * 16 + quad * 4 + rr;
          int c = j * 16 + l15;
          out[(size_t)(b * 8192 + st * 128 + s) * 512 + ct * 128 + c] = acc[i][j][rr];
        }
  }
}

// ------------------------------------------------------------------
extern "C" void kernel_launch(void* const* d_in, const int* in_sizes, int n_in,
                              void* d_out, int out_size, void* d_ws, size_t ws_size,
                              hipStream_t stream) {
  if (ws_size < (size_t)WS_NEED) return;  // need ~65.4 MiB scratch
  const float* x = (const float*)d_in[0];
  const float* W = (const float*)d_in[1];
  float* out = (float*)d_out;
  char* ws = (char*)d_ws;
  u16* eImg = (u16*)(ws + OFF_E);
  u16* eTImg = (u16*)(ws + OFF_ET);
  float* Epart = (float*)(ws + OFF_EPART);
  u16* GtImg = (u16*)(ws + OFF_GT);
  u16* WtImg = (u16*)(ws + OFF_WT);
  float* zpart = (float*)(ws + OFF_ZP);
  float* rz2 = (float*)(ws + OFF_RZ2);

  k_wt<<<256, 256, 0, stream>>>(W, WtImg);
  k_logits_e<<<512, 256, 0, stream>>>(x, WtImg, eImg, eTImg, zpart);
  k_zmerge<<<4, 256, 0, stream>>>(zpart, rz2);
  k_E<<<dim3(4, 8, 16), 256, 0, stream>>>(x, eTImg, Epart);
  k_G<<<256, 256, 0, stream>>>(Epart, rz2, GtImg);
  k_out<<<dim3(64, 8), 256, 0, stream>>>(eImg, GtImg, out);
}

// Round 3
// 301.737 us; speedup vs baseline: 1.0039x; 1.0039x over previous
//
#include <hip/hip_runtime.h>

typedef float  f32x4 __attribute__((ext_vector_type(4)));
typedef short  s16x8 __attribute__((ext_vector_type(8)));
typedef unsigned short u16;

// ---- workspace layout (bytes) ----
#define OFF_E     0ULL            // e  bf16 LDS-image tiles [512][32KiB]   16 MiB
#define OFF_ET    16777216ULL     // eT bf16 image tiles [8][128][16KiB]    16 MiB
#define OFF_EPART 33554432ULL     // Epart f32 [16][8][512][128]            32 MiB
#define OFF_GT    67108864ULL     // Gt bf16 image tiles [8][8][16KiB]       1 MiB
#define OFF_WT    68157440ULL     // Wt bf16 image tiles [8][16KiB]        128 KiB
#define OFF_ZP    68288512ULL     // zpart f32 [512][128]                  256 KiB
#define OFF_RZ2   68550656ULL     // (unused now)                            4 KiB
#define WS_NEED   68554752ULL

// async global->LDS, 16B per lane, wave-uniform LDS base + lane*16
#define GLL16(g, l)                                                          \
  __builtin_amdgcn_global_load_lds(                                          \
      (const __attribute__((address_space(1))) void*)(g),                    \
      (__attribute__((address_space(3))) void*)(l), 16, 0, 0)

// 3-bit octet-permutation key for 64-element (8-octet) rows
#define KEY3(r) ((((r) >> 3) ^ ((r) << 1)) & 7)

__device__ __forceinline__ u16 f2bf(float f) {
  unsigned u = __float_as_uint(f);
  return (u16)((u + 0x8000u) >> 16);          // round-half-up to bf16
}
__device__ __forceinline__ unsigned pack2(float a, float b) {
  unsigned ua = __float_as_uint(a), ub = __float_as_uint(b);
  return ((ua + 0x8000u) >> 16) | ((ub + 0x8000u) & 0xffff0000u);
}

// ------------------------------------------------------------------
// k_wt: Wt stored as k_logits_e's lB LDS image (unchanged layout):
//   img[kt][h*64 + ((oct ^ (h&7))*8) + t] = W[kt*64 + oct*8 + t][h]
__global__ __launch_bounds__(256) void k_wt(const float* __restrict__ W,
                                            u16* __restrict__ WtImg) {
  int idx = blockIdx.x * 256 + threadIdx.x;    // 65536 total
  int h = idx & 127, c = idx >> 7;
  int kt = c >> 6, oct = (c >> 3) & 7, t = c & 7;
  WtImg[kt * 8192 + h * 64 + ((oct ^ (h & 7)) * 8) + t] = f2bf(W[c * 128 + h]);
}

// ------------------------------------------------------------------
// k_logits_e: 2-phase pipelined.  Per kt (64-c K-step): prefetch Wt(kt+1)
// via gll + x(kt+1) into regs, MFMA on current buffers, pack x into the
// other lA buffer, ONE barrier.  Epilogue: e-image (raw dump) + eT-image
// (two 16KiB 64-s tiles per block, 8-octet KEY3 layout for k_E).
__global__ __launch_bounds__(256) void k_logits_e(
    const float* __restrict__ x, const u16* __restrict__ WtImg,
    u16* __restrict__ eImg, u16* __restrict__ eTImg, float* __restrict__ zpart) {
  __shared__ __align__(16) u16 smem[4 * 8192];   // lA0 lA1 lB0 lB1, 16 KiB each
  __shared__ float zs[512];
  u16* const sm = smem;                          // epilogue reuse (32 KiB)
  const int tid = threadIdx.x;
  const int lane = tid & 63, wave = tid >> 6;
  const int l15 = lane & 15, quad = lane >> 4;
  const int mt = blockIdx.x;                   // 0..511  (== b*64 + sc)
  const int rowBase = mt << 7;
  const int q = tid & 3, rb = tid >> 2;

  f32x4 acc[2][8];
#pragma unroll
  for (int i = 0; i < 2; ++i)
#pragma unroll
    for (int j = 0; j < 8; ++j) acc[i][j] = (f32x4){0.f, 0.f, 0.f, 0.f};

  f32x4 xv[2][4];

  // ---- prologue: fill buffers 0
  {
    const char* srcB = (const char*)WtImg + wave * 4096 + lane * 16;
    char* dstB = (char*)(smem + 16384) + wave * 4096;
#pragma unroll
    for (int i = 0; i < 4; ++i) GLL16(srcB + i * 1024, dstB + i * 1024);
  }
#pragma unroll
  for (int rep = 0; rep < 2; ++rep) {
    const int r = rb + rep * 64;
    const float* src = x + (size_t)(rowBase + r) * 512 + q * 4;
#pragma unroll
    for (int j = 0; j < 4; ++j) xv[rep][j] = *(const f32x4*)(src + j * 16);
  }
#pragma unroll
  for (int rep = 0; rep < 2; ++rep) {
    const int r = rb + rep * 64;
#pragma unroll
    for (int j = 0; j < 4; ++j) {
      const int chunk = (2 * j + (q >> 1)) ^ (r & 7);
      unsigned* dst = (unsigned*)&smem[r * 64 + chunk * 8 + (q & 1) * 4];
      dst[0] = pack2(xv[rep][j][0], xv[rep][j][1]);
      dst[1] = pack2(xv[rep][j][2], xv[rep][j][3]);
    }
  }
  __syncthreads();

  for (int kt = 0; kt < 8; ++kt) {
    const int cur = kt & 1;
    u16* lAc = smem + (cur ? 8192 : 0);
    u16* lBc = smem + 16384 + (cur ? 8192 : 0);
    if (kt < 7) {
      // prefetch B(kt+1) via gll into other buffer
      const char* srcB = (const char*)WtImg + (size_t)(kt + 1) * 16384 + wave * 4096 + lane * 16;
      char* dstB = (char*)(smem + 16384 + (cur ? 0 : 8192)) + wave * 4096;
#pragma unroll
      for (int i = 0; i < 4; ++i) GLL16(srcB + i * 1024, dstB + i * 1024);
      // prefetch x(kt+1) into regs
      const int k0 = (kt + 1) << 6;
#pragma unroll
      for (int rep = 0; rep < 2; ++rep) {
        const int r = rb + rep * 64;
        const float* src = x + (size_t)(rowBase + r) * 512 + k0 + q * 4;
#pragma unroll
        for (int j = 0; j < 4; ++j) xv[rep][j] = *(const f32x4*)(src + j * 16);
      }
    }
    // ---- MFMA on current buffers (prefetch loads in flight)
#pragma unroll
    for (int kk = 0; kk < 2; ++kk) {
      s16x8 af[2], bf[8];
#pragma unroll
      for (int i = 0; i < 2; ++i) {
        const int r = wave * 32 + i * 16 + l15;
        af[i] = *(const s16x8*)&lAc[r * 64 + (((kk * 4 + quad) ^ (r & 7)) * 8)];
      }
#pragma unroll
      for (int j = 0; j < 8; ++j) {
        const int r = j * 16 + l15;
        bf[j] = *(const s16x8*)&lBc[r * 64 + (((kk * 4 + quad) ^ (r & 7)) * 8)];
      }
#pragma unroll
      for (int i = 0; i < 2; ++i)
#pragma unroll
        for (int j = 0; j < 8; ++j)
          acc[i][j] = __builtin_amdgcn_mfma_f32_16x16x32_bf16(af[i], bf[j], acc[i][j], 0, 0, 0);
    }
    // ---- pack prefetched x into the other lA buffer
    if (kt < 7) {
      u16* lAn = smem + (cur ? 0 : 8192);
#pragma unroll
      for (int rep = 0; rep < 2; ++rep) {
        const int r = rb + rep * 64;
#pragma unroll
        for (int j = 0; j < 4; ++j) {
          const int chunk = (2 * j + (q >> 1)) ^ (r & 7);
          unsigned* dst = (unsigned*)&lAn[r * 64 + chunk * 8 + (q & 1) * 4];
          dst[0] = pack2(xv[rep][j][0], xv[rep][j][1]);
          dst[1] = pack2(xv[rep][j][2], xv[rep][j][3]);
        }
      }
    }
    __syncthreads();
  }

  float ex[2][8][4];
  float cs[8];
#pragma unroll
  for (int j = 0; j < 8; ++j) cs[j] = 0.f;
#pragma unroll
  for (int i = 0; i < 2; ++i)
#pragma unroll
    for (int j = 0; j < 8; ++j)
#pragma unroll
      for (int rr = 0; rr < 4; ++rr) {
        float l = acc[i][j][rr];
        l = fminf(fmaxf(l, -30.f), 30.f);
        float t = __expf(l);
        ex[i][j][rr] = t;
        cs[j] += t;
      }
#pragma unroll
  for (int j = 0; j < 8; ++j) {
    cs[j] += __shfl_xor(cs[j], 16);
    cs[j] += __shfl_xor(cs[j], 32);
  }
  if (quad == 0) {
#pragma unroll
    for (int j = 0; j < 8; ++j) zs[wave * 128 + j * 16 + l15] = cs[j];
  }
  __syncthreads();

#pragma unroll
  for (int i = 0; i < 2; ++i)
#pragma unroll
    for (int j = 0; j < 8; ++j)
#pragma unroll
      for (int rr = 0; rr < 4; ++rr) {
        int s = wave * 32 + i * 16 + quad * 4 + rr;
        int h = j * 16 + l15;
        sm[s * 128 + (((h >> 3) ^ (s & 15)) * 8) + (h & 7)] = f2bf(ex[i][j][rr]);
      }
  if (tid < 128)
    zpart[mt * 128 + tid] = zs[tid] + zs[128 + tid] + zs[256 + tid] + zs[384 + tid];
  __syncthreads();

  // ---- e image: raw linear dump of sm (sm layout == k_out lA image)
  {
    char* dstT = (char*)eImg + (size_t)mt * 32768;
    const char* smB = (const char*)sm;
#pragma unroll
    for (int pass = 0; pass < 8; ++pass) {
      s16x8 v = *(const s16x8*)(smB + pass * 4096 + tid * 16);
      *(s16x8*)(dstT + pass * 4096 + tid * 16) = v;
    }
  }
  // ---- eT image: gather transpose into two 16KiB 64-s tiles (KEY3 layout)
  {
    int ck = tid & 15, hb = tid >> 4;
    int cH = ck >> 3, oct = ck & 7;
    u16* dstT = eTImg + (size_t)mt * 16384 + cH * 8192;
#pragma unroll
    for (int pass = 0; pass < 8; ++pass) {
      int h = hb + pass * 16;
      s16x8 v;
#pragma unroll
      for (int j = 0; j < 8; ++j) {
        int s = ck * 8 + j;
        v[j] = (short)sm[s * 128 + (((h >> 3) ^ (s & 15)) * 8) + (h & 7)];
      }
      *(s16x8*)(dstT + h * 64 + ((oct ^ KEY3(h)) * 8)) = v;
    }
  }
}

// ------------------------------------------------------------------
// k_E: E^T[c][h] = sum_s x[s][c]*eT[h][s].  2-phase pipelined, 64-s K-steps.
// eT via gll from pre-swizzled image; x fp32 loaded to regs one step ahead,
// transpose-packed into the other lA buffer.  One barrier per step.
__global__ __launch_bounds__(256) void k_E(const float* __restrict__ x,
                                           const u16* __restrict__ eTImg,
                                           float* __restrict__ Epart) {
  __shared__ __align__(16) u16 smem[4 * 8192];   // lA0 lA1 lB0 lB1, 16 KiB each
  const int tid = threadIdx.x;
  const int lane = tid & 63, wave = tid >> 6;
  const int l15 = lane & 15, quad = lane >> 4;
  const int nt = blockIdx.x;   // c band 0..3 (128 wide)
  const int b = blockIdx.y;
  const int kc = blockIdx.z;   // 0..15: 512-s chunk
  const int cw = tid & 15, rg = tid >> 4;   // A-stage: c-octet / 4-s group

  f32x4 acc[2][8];
#pragma unroll
  for (int i = 0; i < 2; ++i)
#pragma unroll
    for (int j = 0; j < 8; ++j) acc[i][j] = (f32x4){0.f, 0.f, 0.f, 0.f};

  f32x4 xv[4][2];

  // ---- prologue: fill buffers 0 (s-chunk kt=0)
  {
    const char* srcB = (const char*)eTImg + ((size_t)(b * 128 + kc * 8) * 16384) +
                       wave * 4096 + lane * 16;
    char* dstB = (char*)(smem + 16384) + wave * 4096;
#pragma unroll
    for (int i = 0; i < 4; ++i) GLL16(srcB + i * 1024, dstB + i * 1024);
  }
  {
    const float* src = x + ((size_t)(b * 8192 + kc * 512 + rg * 4) * 512 + nt * 128 + cw * 8);
#pragma unroll
    for (int j = 0; j < 4; ++j) {
      xv[j][0] = *(const f32x4*)(src + (size_t)j * 512);
      xv[j][1] = *(const f32x4*)(src + (size_t)j * 512 + 4);
    }
  }
#pragma unroll
  for (int i = 0; i < 8; ++i) {
    const int cl = cw * 8 + i;
    unsigned wv[2];
    if (i < 4) {
      wv[0] = pack2(xv[0][0][i], xv[1][0][i]);
      wv[1] = pack2(xv[2][0][i], xv[3][0][i]);
    } else {
      wv[0] = pack2(xv[0][1][i - 4], xv[1][1][i - 4]);
      wv[1] = pack2(xv[2][1][i - 4], xv[3][1][i - 4]);
    }
    *(unsigned*)&smem[cl * 64 + (((rg >> 1) ^ KEY3(cl)) * 8) + (rg & 1) * 4] = wv[0];
    *(unsigned*)&smem[cl * 64 + (((rg >> 1) ^ KEY3(cl)) * 8) + (rg & 1) * 4 + 2] = wv[1];
  }
  __syncthreads();

  for (int kt = 0; kt < 8; ++kt) {          // 8 steps of 64 s
    const int cur = kt & 1;
    u16* lAc = smem + (cur ? 8192 : 0);
    u16* lBc = smem + 16384 + (cur ? 8192 : 0);
    if (kt < 7) {
      const char* srcB = (const char*)eTImg +
                         ((size_t)(b * 128 + kc * 8 + kt + 1) * 16384) +
                         wave * 4096 + lane * 16;
      char* dstB = (char*)(smem + 16384 + (cur ? 0 : 8192)) + wave * 4096;
#pragma unroll
      for (int i = 0; i < 4; ++i) GLL16(srcB + i * 1024, dstB + i * 1024);
      const float* src = x + ((size_t)(b * 8192 + kc * 512 + (kt + 1) * 64 + rg * 4) * 512 +
                              nt * 128 + cw * 8);
#pragma unroll
      for (int j = 0; j < 4; ++j) {
        xv[j][0] = *(const f32x4*)(src + (size_t)j * 512);
        xv[j][1] = *(const f32x4*)(src + (size_t)j * 512 + 4);
      }
    }
    // ---- MFMA on current buffers
#pragma unroll
    for (int kk = 0; kk < 2; ++kk) {
      s16x8 af[2], bf[8];
#pragma unroll
      for (int i = 0; i < 2; ++i) {
        const int r = wave * 32 + i * 16 + l15;
        af[i] = *(const s16x8*)&lAc[r * 64 + (((kk * 4 + quad) ^ KEY3(r)) * 8)];
      }
#pragma unroll
      for (int j = 0; j < 8; ++j) {
        const int n = j * 16 + l15;
        bf[j] = *(const s16x8*)&lBc[n * 64 + (((kk * 4 + quad) ^ KEY3(n)) * 8)];
      }
#pragma unroll
      for (int i = 0; i < 2; ++i)
#pragma unroll
        for (int j = 0; j < 8; ++j)
          acc[i][j] = __builtin_amdgcn_mfma_f32_16x16x32_bf16(af[i], bf[j], acc[i][j], 0, 0, 0);
    }
    // ---- pack prefetched x into other lA buffer
    if (kt < 7) {
      u16* lAn = smem + (cur ? 0 : 8192);
#pragma unroll
      for (int i = 0; i < 8; ++i) {
        const int cl = cw * 8 + i;
        unsigned wv[2];
        if (i < 4) {
          wv[0] = pack2(xv[0][0][i], xv[1][0][i]);
          wv[1] = pack2(xv[2][0][i], xv[3][0][i]);
        } else {
          wv[0] = pack2(xv[0][1][i - 4], xv[1][1][i - 4]);
          wv[1] = pack2(xv[2][1][i - 4], xv[3][1][i - 4]);
        }
        *(unsigned*)&lAn[cl * 64 + (((rg >> 1) ^ KEY3(cl)) * 8) + (rg & 1) * 4] = wv[0];
        *(unsigned*)&lAn[cl * 64 + (((rg >> 1) ^ KEY3(cl)) * 8) + (rg & 1) * 4 + 2] = wv[1];
      }
    }
    __syncthreads();
  }
  float* dst = Epart + ((size_t)(kc * 8 + b) * 512 + nt * 128) * 128;
#pragma unroll
  for (int i = 0; i < 2; ++i)
#pragma unroll
    for (int j = 0; j < 8; ++j)
#pragma unroll
      for (int rr = 0; rr < 4; ++rr) {
        int c = wave * 32 + i * 16 + quad * 4 + rr;
        int h = j * 16 + l15;
        dst[(size_t)c * 128 + h] = acc[i][j][rr];
      }
}

// ------------------------------------------------------------------
// k_G (+fused zmerge): rz2 computed in-block (exact same sum order),
// Gt image written as [8 ct][64 c][128 h] 16KiB tiles for k_out.
__global__ __launch_bounds__(256) void k_G(const float* __restrict__ Epart,
                                           const float* __restrict__ zpart,
                                           u16* __restrict__ GtImg) {
  __shared__ float rzs[128];
  const int tid = threadIdx.x;
  const int bidx = blockIdx.x;        // 0..255, b uniform per block
  const int b = bidx >> 5;
  if (tid < 128) {
    float z = 0.f;
#pragma unroll 8
    for (int i = 0; i < 64; ++i) z += zpart[(b * 64 + i) * 128 + tid];
    rzs[tid] = 1.0f / (z * z);
  }
  __syncthreads();
  int idx = bidx * 256 + tid;
  int h8 = idx & 15, c = (idx >> 4) & 511;
  f32x4 s0 = {0.f, 0.f, 0.f, 0.f}, s1 = {0.f, 0.f, 0.f, 0.f};
#pragma unroll
  for (int p = 0; p < 16; ++p) {
    const float* src = Epart + (((size_t)(p * 8 + b) * 512 + c) * 128 + h8 * 8);
    s0 += *(const f32x4*)src;
    s1 += *(const f32x4*)(src + 4);
  }
  f32x4 z0 = *(const f32x4*)&rzs[h8 * 8];
  f32x4 z1 = *(const f32x4*)&rzs[h8 * 8 + 4];
  unsigned ov[4];
  ov[0] = pack2(s0[0] * z0[0], s0[1] * z0[1]);
  ov[1] = pack2(s0[2] * z0[2], s0[3] * z0[3]);
  ov[2] = pack2(s1[0] * z1[0], s1[1] * z1[1]);
  ov[3] = pack2(s1[2] * z1[2], s1[3] * z1[3]);
  int r = c & 63, ct = c >> 6;
  *(s16x8*)(GtImg + ((size_t)(b * 8 + ct) * 8192) + r * 128 + ((h8 ^ (r & 15)) * 8)) =
      *(s16x8*)ov;
}

// ------------------------------------------------------------------
// k_out: out[s][c] = e[s][:] @ G[:, c].  2-phase pipelined over 8 ct steps
// of 64 c; Gt(ct+1) gll-prefetched during MFMA(ct).  Non-temporal out.
__global__ __launch_bounds__(256) void k_out(const u16* __restrict__ eImg,
                                             const u16* __restrict__ GtImg,
                                             float* __restrict__ out) {
  __shared__ __align__(16) u16 lA[128 * 128];      // 32 KiB (e tile)
  __shared__ __align__(16) u16 lBd[2 * 64 * 128];  // 2 × 16 KiB (Gt tiles)
  const int tid = threadIdx.x;
  const int lane = tid & 63, wave = tid >> 6;
  const int l15 = lane & 15, quad = lane >> 4;
  const int st = blockIdx.x;
  const int b = blockIdx.y;

  // ---- prologue: stage A (e image, once) + B(ct=0)
  {
    const char* src = (const char*)eImg + ((size_t)(b * 64 + st) * 32768) +
                      wave * 8192 + lane * 16;
    char* dst = (char*)lA + wave * 8192;
#pragma unroll
    for (int i = 0; i < 8; ++i) GLL16(src + i * 1024, dst + i * 1024);
  }
  {
    const char* src = (const char*)GtImg + ((size_t)(b * 8) * 16384) +
                      wave * 4096 + lane * 16;
    char* dst = (char*)lBd + wave * 4096;
#pragma unroll
    for (int i = 0; i < 4; ++i) GLL16(src + i * 1024, dst + i * 1024);
  }
  __syncthreads();

  for (int ct = 0; ct < 8; ++ct) {
    const int cur = ct & 1;
    u16* lBc = lBd + (cur ? 8192 : 0);
    if (ct < 7) {
      const char* src = (const char*)GtImg + ((size_t)(b * 8 + ct + 1) * 16384) +
                        wave * 4096 + lane * 16;
      char* dst = (char*)(lBd + (cur ? 0 : 8192)) + wave * 4096;
#pragma unroll
      for (int i = 0; i < 4; ++i) GLL16(src + i * 1024, dst + i * 1024);
    }
    f32x4 acc[2][4];
#pragma unroll
    for (int i = 0; i < 2; ++i)
#pragma unroll
      for (int j = 0; j < 4; ++j) acc[i][j] = (f32x4){0.f, 0.f, 0.f, 0.f};
#pragma unroll
    for (int kk = 0; kk < 4; ++kk) {
      s16x8 af[2], bf[4];
#pragma unroll
      for (int i = 0; i < 2; ++i) {
        const int r = wave * 32 + i * 16 + l15;
        af[i] = *(const s16x8*)&lA[r * 128 + (((kk * 4 + quad) ^ (r & 15)) * 8)];
      }
#pragma unroll
      for (int j = 0; j < 4; ++j) {
        const int n = j * 16 + l15;
        bf[j] = *(const s16x8*)&lBc[n * 128 + (((kk * 4 + quad) ^ (n & 15)) * 8)];
      }
#pragma unroll
      for (int i = 0; i < 2; ++i)
#pragma unroll
        for (int j = 0; j < 4; ++j)
          acc[i][j] = __builtin_amdgcn_mfma_f32_16x16x32_bf16(af[i], bf[j], acc[i][j], 0, 0, 0);
    }
#pragma unroll
    for (int i = 0; i < 2; ++i)
#pragma unroll
      for (int j = 0; j < 4; ++j)
#pragma unroll
        for (int rr = 0; rr < 4; ++rr) {
          int s = wave * 32 + i * 16 + quad * 4 + rr;
          int c = ct * 64 + j * 16 + l15;
          __builtin_nontemporal_store(
              acc[i][j][rr], &out[(size_t)(b * 8192 + st * 128 + s) * 512 + c]);
        }
    __syncthreads();
  }
}

// ------------------------------------------------------------------
extern "C" void kernel_launch(void* const* d_in, const int* in_sizes, int n_in,
                              void* d_out, int out_size, void* d_ws, size_t ws_size,
                              hipStream_t stream) {
  if (ws_size < (size_t)WS_NEED) return;  // need ~65.4 MiB scratch
  const float* x = (const float*)d_in[0];
  const float* W = (const float*)d_in[1];
  float* out = (float*)d_out;
  char* ws = (char*)d_ws;
  u16* eImg = (u16*)(ws + OFF_E);
  u16* eTImg = (u16*)(ws + OFF_ET);
  float* Epart = (float*)(ws + OFF_EPART);
  u16* GtImg = (u16*)(ws + OFF_GT);
  u16* WtImg = (u16*)(ws + OFF_WT);
  float* zpart = (float*)(ws + OFF_ZP);

  k_wt<<<256, 256, 0, stream>>>(W, WtImg);
  k_logits_e<<<512, 256, 0, stream>>>(x, WtImg, eImg, eTImg, zpart);
  k_E<<<dim3(4, 8, 16), 256, 0, stream>>>(x, eTImg, Epart);
  k_G<<<256, 256, 0, stream>>>(Epart, zpart, GtImg);
  k_out<<<dim3(64, 8), 256, 0, stream>>>(eImg, GtImg, out);
}